// Round 9
// baseline (132.681 us; speedup 1.0000x reference)
//
#include <hip/hip_runtime.h>

#define NN 4096
#define NC 10
#define NW 64            // u64 words per adjacency row
#define CHW 16           // words per wave K-chunk (NW/4)
#define BH 32            // tile = 32x32 pairs, 64 rows staged
typedef unsigned long long u64;
typedef long long s64;

#define S1F 0.73105857863000489f   // sigmoid(1.0)

// ws layout (bytes)
#define OFF_BITS   0           // 4096*64*8 = 2097152
#define OFF_DEG    2097152     // int[4096]
#define OFF_POS    2113536     // float[4096]
#define OFF_LIST   2129920     // int[4096]
#define OFF_ACC    2146304     // 1536 B strip (memset 0 each call)
#define OFF_CNT    2147840     // int[10][4096] = 163840 (memset 0, contiguous)
// acc strip offsets
#define A_CE    0
#define A_LOSS  4
#define A_MCNT  8
#define A_NCNT  16    // 10 ints
#define A_GD    64    // 10 ints
#define A_GE    128   // 100 ints
#define A_GSI   528   // 100 u64

// ---- kernel 1: pack bits + degrees + class-count table (masked rows only) -
// Only masked rows' bits/deg are ever read downstream -> skip unmasked rows
// entirely (halves adj HBM traffic).
__global__ __launch_bounds__(256) void pack_bits_kernel(
    const int* __restrict__ adj, u64* __restrict__ bits, int* __restrict__ deg,
    int* __restrict__ cnt, const int* __restrict__ labels,
    const int* __restrict__ mask) {
  int p = blockIdx.x;
  if (mask[p] == 0) return;
  int tid = threadIdx.x;
  int wv = tid >> 6, lane = tid & 63;
  const int* row = adj + (size_t)p * NN;
  int lb = labels[p];
  int c = 0;
  for (int w = wv; w < NW; w += 4) {
    int a = row[(w << 6) + lane];
    u64 b = __ballot(a != 0);
    if (lane == 0) bits[(size_t)p * NW + w] = b;
    if (a != 0) { c++; atomicAdd(&cnt[lb * NN + (w << 6) + lane], 1); }
  }
  __shared__ int red[256];
  red[tid] = c;
  __syncthreads();
  for (int s = 128; s > 0; s >>= 1) {
    if (tid < s) red[tid] += red[tid + s];
    __syncthreads();
  }
  if (tid == 0) deg[p] = red[0];
}

// ---- kernel 2 (merged): node CE/pos/Ncnt (blk 0-15), compaction (blk 16),
//      class-pair aggregates (blk 17-32) ---------------------------------
__global__ __launch_bounds__(256) void mid_kernel(
    const float* __restrict__ preds, const int* __restrict__ labels,
    const int* __restrict__ mask, const u64* __restrict__ bits,
    const int* __restrict__ deg, const int* __restrict__ cnt,
    float* __restrict__ pos, int* __restrict__ Ncnt, float* __restrict__ ceAcc,
    int* __restrict__ list, int* __restrict__ Mcount,
    u64* __restrict__ gSI, int* __restrict__ gE, int* __restrict__ gD) {
  int tid = threadIdx.x;
  int blk = blockIdx.x;
  if (blk < 16) {                              // per-node CE + pos + Ncnt
    int n = blk * 256 + tid;
    int l = labels[n];
    float r[NC];
    float mx = -1e30f, rl = 0.f;
#pragma unroll
    for (int c = 0; c < NC; c++) {
      float v = preds[n * NC + c];
      r[c] = v;
      if (c == l) rl = v;
      mx = fmaxf(mx, v);
    }
    float s = 0.f;
#pragma unroll
    for (int c = 0; c < NC; c++) s += expf(r[c] - mx);
    pos[n] = rl;
    float ce = mx + logf(s) - rl;
    if (mask[n] != 0) atomicAdd(&Ncnt[l], 1);
    __shared__ float red[256];
    red[tid] = ce;
    __syncthreads();
    for (int st = 128; st > 0; st >>= 1) {
      if (tid < st) red[tid] += red[tid + st];
      __syncthreads();
    }
    if (tid == 0) atomicAdd(ceAcc, red[0]);
  } else if (blk == 16) {                      // deterministic compaction
    __shared__ int cnt2[256];
    int base = tid * 16;
    int c = 0;
    for (int i = 0; i < 16; i++) c += (mask[base + i] != 0) ? 1 : 0;
    cnt2[tid] = c;
    __syncthreads();
    for (int s = 1; s < 256; s <<= 1) {
      int v = (tid >= s) ? cnt2[tid - s] : 0;
      __syncthreads();
      cnt2[tid] += v;
      __syncthreads();
    }
    int off = cnt2[tid] - c;
    for (int i = 0; i < 16; i++) {
      int idx = base + i;
      if (mask[idx] != 0) list[off++] = idx;
    }
    if (tid == 255) *Mcount = cnt2[255];
  } else {                                     // class aggregates
    __shared__ int eb[100], db[10];
    for (int b = tid; b < 100; b += 256) eb[b] = 0;
    if (tid < 10) db[tid] = 0;
    __syncthreads();
    int r = (blk - 17) * 256 + tid;
    int c[10];
#pragma unroll
    for (int i = 0; i < NC; i++) c[i] = cnt[i * NN + r];
    int sI[55];
    {
      int k = 0;
#pragma unroll
      for (int i = 0; i < NC; i++)
#pragma unroll
        for (int j = i; j < NC; j++) { sI[k] = c[i] * c[j]; k++; }
    }
#pragma unroll
    for (int k = 0; k < 55; k++) {
      int v = sI[k];
      for (int d = 1; d < 64; d <<= 1) v += __shfl_xor(v, d);
      sI[k] = v;
    }
    if ((tid & 63) == 0) {
      int k = 0;
      for (int i = 0; i < NC; i++)
        for (int j = i; j < NC; j++) {
          u64 v = (u64)(unsigned int)sI[k];
          if (v) {
            atomicAdd(&gSI[i * NC + j], v);
            if (i != j) atomicAdd(&gSI[j * NC + i], v);
          }
          k++;
        }
    }
    if (mask[r] != 0) {
      int lr = labels[r];
      atomicAdd(&db[lr], deg[r]);
      int selfr = (int)((bits[(size_t)r * NW + (r >> 6)] >> (r & 63)) & 1ULL);
      if (!selfr) {
#pragma unroll
        for (int i = 0; i < NC; i++)
          if (c[i]) atomicAdd(&eb[i * NC + lr], c[i]);
      }
    }
    __syncthreads();
    for (int b = tid; b < 100; b += 256) if (eb[b]) atomicAdd(&gE[b], eb[b]);
    if (tid < 10 && db[tid]) atomicAdd(&gD[tid], db[tid]);
  }
}

// ---- kernel 3: split-K 32x32 pair tiles (1 tile/block, 4 waves) -----------
// Wave wv computes the 16-word K-chunk [wv*16, wv*16+16) of all 1024 pair
// popcounts; partials exchanged via column-major LDS; each thread then
// reduces + epilogues 4 pairs. All epilogue scatter data prefetched into
// registers BEFORE the popc loop (latency hides under ~2K cy of popcount).
// 8320 wave-units at M=2048 (vs 2080 in R8) -> latency overlap via 12
// waves/CU instead of 2 waves/SIMD total.
__global__ __launch_bounds__(256, 3) void pair_kernel(
    const u64* __restrict__ bits, const int* __restrict__ deg,
    const float* __restrict__ pos, const float* __restrict__ preds,
    const int* __restrict__ labels, const int* __restrict__ list,
    const int* __restrict__ Mcount, const int* __restrict__ Ncnt,
    const u64* __restrict__ gSI, const int* __restrict__ gE,
    const int* __restrict__ gD, float* __restrict__ gLoss) {
  __shared__ __align__(16) u64 TBW[4][CHW][64];   // 32 KB word-major bit tiles
  __shared__ int accX[4][CHW][65];                // 16.6 KB partial popcounts
  __shared__ float wLDS[100];
  __shared__ float wred[4];

  int tid = threadIdx.x;
  int wv = tid >> 6, lane = tid & 63;

  // class-pair weights from exact integer aggregates (gate + PER/(Ni*Nj))
  if (tid < 100) {
    int i = tid / NC, j = tid - (tid / NC) * NC;
    s64 SI = (s64)gSI[tid];
    s64 ssub = (s64)gD[i] * (s64)Ncnt[j] - SI - (s64)gE[tid];
    float w = 0.f;
    if (i != j && ssub > 0 && SI > 0) {
      float Ni = fmaxf((float)Ncnt[i], 1.f);
      float Nj = fmaxf((float)Ncnt[j], 1.f);
      w = 0.001f / (Ni * Nj);
    }
    wLDS[tid] = w;
  }
  __syncthreads();

  int M = *Mcount;
  int ntp = (M + BH - 1) / BH;
  int ntiles = (ntp * (ntp + 1)) >> 1;

  int lp = lane >> 3, lq = lane & 7;          // 8x8 lane grid, 4x4 pairs each
  // swizzled 16B-unit slots: sigma(u) = u ^ ((u>>3)&1)
  int uP0 = 2 * lp, uP1 = 2 * lp + 1;
  int uQ0 = 16 + 2 * lq, uQ1 = 17 + 2 * lq;
  int rdP0 = (uP0 ^ ((uP0 >> 3) & 1)) << 1;
  int rdP1 = (uP1 ^ ((uP1 >> 3) & 1)) << 1;
  int rdQ0 = (uQ0 ^ ((uQ0 >> 3) & 1)) << 1;
  int rdQ1 = (uQ1 ^ ((uQ1 >> 3) & 1)) << 1;
  int uw = lane >> 1;
  int wslot = ((uw ^ ((uw >> 3) & 1)) << 1) + (lane & 1);

  float lsum = 0.f;

  for (int t = blockIdx.x; t < ntiles; t += gridDim.x) {
    int tp = 0, rem = t;
    while (rem >= ntp - tp) { rem -= ntp - tp; tp++; }
    int tq = tp + rem;
    bool diag = (tp == tq);

    // ---- staging: my row = lane (0-31 P band, 32-63 Q band), chunk = wv
    int mi = (lane < BH) ? (tp * BH + lane) : (tq * BH + (lane - BH));
    int nd = (mi < M) ? list[mi] : -1;
    const u64* rowp = bits + (size_t)((nd >= 0) ? nd : 0) * NW + wv * CHW;
    bool live = (nd >= 0);
    ulonglong2 pf[8];
#pragma unroll
    for (int x = 0; x < 8; x++)
      pf[x] = live ? *(const ulonglong2*)(rowp + (x << 1))
                   : make_ulonglong2(0ULL, 0ULL);

    // ---- epilogue prefetch: my 4 pairs are (P row pl, Q rows 4*lq+j)
    int pl = (lp << 2) + wv;
    int miP = tp * BH + pl;
    int pgE = (miP < M) ? list[miP] : -1;
    int pgi = (pgE >= 0) ? pgE : 0;
    int liE = labels[pgi];
    int dgpE = deg[pgi];
    float ppE = pos[pgi];
    int spE = (int)((bits[(size_t)pgi * NW + (pgi >> 6)] >> (pgi & 63)) & 1ULL);
    int qgE[4], ljE[4], dgqE[4], sqE[4];
    float pqE[4], efE[4], erE[4];
    u64 rwpE[4], rwqE[4];
#pragma unroll
    for (int j = 0; j < 4; j++) {
      int miQ = tq * BH + (lq << 2) + j;
      int qg = (miQ < M) ? list[miQ] : -1;
      qgE[j] = qg;
      int qi = (qg >= 0) ? qg : 0;
      ljE[j] = labels[qi];
      dgqE[j] = deg[qi];
      pqE[j] = pos[qi];
      sqE[j] = (int)((bits[(size_t)qi * NW + (qi >> 6)] >> (qi & 63)) & 1ULL);
      rwpE[j] = bits[(size_t)pgi * NW + (qi >> 6)];
      rwqE[j] = bits[(size_t)qi * NW + (pgi >> 6)];
      efE[j] = preds[qi * NC + liE];
      erE[j] = preds[pgi * NC + ljE[j]];
    }

    // ---- LDS staging writes (wave-local slice, word-major swizzled)
#pragma unroll
    for (int x = 0; x < 8; x++) {
      TBW[wv][2 * x][wslot]     = pf[x].x;
      TBW[wv][2 * x + 1][wslot] = pf[x].y;
    }
    asm volatile("s_waitcnt lgkmcnt(0)" ::: "memory");
    __builtin_amdgcn_sched_barrier(0);

    // ---- popc over my 16-word chunk, all 16 pairs
    int acc[16];
#pragma unroll
    for (int k = 0; k < 16; k++) acc[k] = 0;
#pragma unroll 4
    for (int y = 0; y < CHW; y++) {
      ulonglong2 P0 = *(ulonglong2*)&TBW[wv][y][rdP0];
      ulonglong2 P1 = *(ulonglong2*)&TBW[wv][y][rdP1];
      ulonglong2 Q0 = *(ulonglong2*)&TBW[wv][y][rdQ0];
      ulonglong2 Q1 = *(ulonglong2*)&TBW[wv][y][rdQ1];
      u64 p[4] = {P0.x, P0.y, P1.x, P1.y};
      u64 q[4] = {Q0.x, Q0.y, Q1.x, Q1.y};
#pragma unroll
      for (int i = 0; i < 4; i++)
#pragma unroll
        for (int j = 0; j < 4; j++)
          acc[i * 4 + j] += (int)__popcll(p[i] & q[j]);
    }

    // ---- exchange partials (column-major: conflict-free b32)
#pragma unroll
    for (int k = 0; k < 16; k++) accX[wv][k][lane] = acc[k];
    __syncthreads();

    // ---- reduce + epilogue: my 4 pairs (i = wv, j = 0..3)
#pragma unroll
    for (int j = 0; j < 4; j++) {
      int kk = (wv << 2) + j;
      int inter = accX[0][kk][lane] + accX[1][kk][lane]
                + accX[2][kk][lane] + accX[3][kk][lane];
      int qr = (lq << 2) + j;
      if (pgE < 0 || qgE[j] < 0) continue;
      int lj = ljE[j];
      if (liE == lj) continue;                // off-diag class bins only
      if (diag && pl >= qr) continue;         // unordered once on diag tiles
      int apq = (int)((rwpE[j] >> (qgE[j] & 63)) & 1ULL);
      int aqp = (int)((rwqE[j] >> (pgE & 63)) & 1ULL);
      int sub_f = dgpE - inter - (apq & (sqE[j] ^ 1));
      int sub_r = dgqE[j] - inter - (aqp & (spE ^ 1));
      float rden = 1.f / (1.f + S1F * (float)inter);
      float xf = (1.f + S1F * (float)sub_f) * rden;
      float xr = (1.f + S1F * (float)sub_r) * rden;
      float Ef = __expf(efE[j] - ppE);
      float Er = __expf(erE[j] - pqE[j]);
      float vf = 1.f / (1.f + __expf(xf));    // 1 - sigmoid(x)
      float vr = 1.f / (1.f + __expf(xr));
      lsum += Ef * vf * wLDS[liE * NC + lj] + Er * vr * wLDS[lj * NC + liE];
    }
    __syncthreads();                          // protect accX before next tile
  }

  // block reduce: wave shuffle -> 4 partials -> one atomic
  for (int d = 1; d < 64; d <<= 1) lsum += __shfl_xor(lsum, d);
  if (lane == 0) wred[wv] = lsum;
  __syncthreads();
  if (tid == 0) atomicAdd(gLoss, wred[0] + wred[1] + wred[2] + wred[3]);
}

// ---- kernel 4: final assembly ---------------------------------------------
__global__ void fin_kernel(const float* __restrict__ ceAcc,
                           const float* __restrict__ gLoss,
                           float* __restrict__ out) {
  out[0] = ceAcc[0] / (float)NN + gLoss[0];
}

// ---- launch ---------------------------------------------------------------
extern "C" void kernel_launch(void* const* d_in, const int* in_sizes, int n_in,
                              void* d_out, int out_size, void* d_ws, size_t ws_size,
                              hipStream_t stream) {
  const float* preds  = (const float*)d_in[0];
  const int*   labels = (const int*)d_in[1];
  const int*   mask   = (const int*)d_in[2];
  const int*   adj    = (const int*)d_in[3];

  char* ws = (char*)d_ws;
  u64*   bits  = (u64*)(ws + OFF_BITS);
  int*   deg   = (int*)(ws + OFF_DEG);
  float* pos   = (float*)(ws + OFF_POS);
  int*   list  = (int*)(ws + OFF_LIST);
  char*  accb  = ws + OFF_ACC;
  float* ceAcc = (float*)(accb + A_CE);
  float* gLoss = (float*)(accb + A_LOSS);
  int*   Mcnt  = (int*)(accb + A_MCNT);
  int*   Ncnt  = (int*)(accb + A_NCNT);
  int*   gD    = (int*)(accb + A_GD);
  int*   gE    = (int*)(accb + A_GE);
  u64*   gSI   = (u64*)(accb + A_GSI);
  int*   cnt   = (int*)(ws + OFF_CNT);

  hipMemsetAsync(ws + OFF_ACC, 0, 1536 + 163840, stream);

  hipLaunchKernelGGL(pack_bits_kernel, dim3(NN), dim3(256), 0, stream,
                     adj, bits, deg, cnt, labels, mask);
  hipLaunchKernelGGL(mid_kernel, dim3(33), dim3(256), 0, stream,
                     preds, labels, mask, bits, deg, cnt,
                     pos, Ncnt, ceAcc, list, Mcnt, gSI, gE, gD);
  // 1 tile/block: M=2048 -> 2080 tiles; block-stride covers up to 8256
  hipLaunchKernelGGL(pair_kernel, dim3(2080), dim3(256), 0, stream,
                     bits, deg, pos, preds, labels, list, Mcnt, Ncnt,
                     gSI, gE, gD, gLoss);
  hipLaunchKernelGGL(fin_kernel, dim3(1), dim3(1), 0, stream,
                     ceAcc, gLoss, (float*)d_out);
}

// Round 10
// 114.704 us; speedup vs baseline: 1.1567x; 1.1567x over previous
//
#include <hip/hip_runtime.h>

#define NN 4096
#define NC 10
#define NW 64            // u64 words per adjacency row
#define CHW 16           // words per chunk (8 ulonglong2)
#define NCHUNK 4
#define BH 32            // tile = 32x32 pairs, 64 rows staged
typedef unsigned long long u64;
typedef long long s64;

#define S1F 0.73105857863000489f   // sigmoid(1.0)

// ws layout (bytes)
#define OFF_BITS   0           // 4096*64*8 = 2097152
#define OFF_DEG    2097152     // int[4096]
#define OFF_POS    2113536     // float[4096]
#define OFF_LIST   2129920     // int[4096]
#define OFF_ACC    2146304     // 1536 B strip
#define OFF_CNT    2147840     // int[10][4096] = 163840 (memset with acc)
// acc strip offsets
#define A_CE    0
#define A_LOSS  4
#define A_MCNT  8
#define A_NCNT  16    // 10 ints
#define A_GD    64    // 10 ints
#define A_GE    128   // 100 ints
#define A_GSI   528   // 100 u64

// ---- kernel 1: pack bits + degrees + class-count table (masked rows only) -
__global__ __launch_bounds__(256) void pack_bits_kernel(
    const int* __restrict__ adj, u64* __restrict__ bits, int* __restrict__ deg,
    int* __restrict__ cnt, const int* __restrict__ labels,
    const int* __restrict__ mask) {
  int p = blockIdx.x;
  if (mask[p] == 0) return;
  int tid = threadIdx.x;
  int wv = tid >> 6, lane = tid & 63;
  const int* row = adj + (size_t)p * NN;
  int lb = labels[p];
  int c = 0;
  for (int w = wv; w < NW; w += 4) {
    int a = row[(w << 6) + lane];
    u64 b = __ballot(a != 0);
    if (lane == 0) bits[(size_t)p * NW + w] = b;
    if (a != 0) { c++; atomicAdd(&cnt[lb * NN + (w << 6) + lane], 1); }
  }
  __shared__ int red[256];
  red[tid] = c;
  __syncthreads();
  for (int s = 128; s > 0; s >>= 1) {
    if (tid < s) red[tid] += red[tid + s];
    __syncthreads();
  }
  if (tid == 0) deg[p] = red[0];
}

// ---- kernel 2 (merged): node CE/pos/Ncnt (blk 0-15), compaction (blk 16),
//      class-pair aggregates (blk 17-32) -----------------------------------
__global__ __launch_bounds__(256) void mid_kernel(
    const float* __restrict__ preds, const int* __restrict__ labels,
    const int* __restrict__ mask, const u64* __restrict__ bits,
    const int* __restrict__ deg, const int* __restrict__ cnt,
    float* __restrict__ pos, int* __restrict__ Ncnt, float* __restrict__ ceAcc,
    int* __restrict__ list, int* __restrict__ Mcount,
    u64* __restrict__ gSI, int* __restrict__ gE, int* __restrict__ gD) {
  int tid = threadIdx.x;
  int blk = blockIdx.x;
  if (blk < 16) {                              // per-node CE + pos + Ncnt
    int n = blk * 256 + tid;
    int l = labels[n];
    float r[NC];
    float mx = -1e30f, rl = 0.f;
#pragma unroll
    for (int c = 0; c < NC; c++) {
      float v = preds[n * NC + c];
      r[c] = v;
      if (c == l) rl = v;
      mx = fmaxf(mx, v);
    }
    float s = 0.f;
#pragma unroll
    for (int c = 0; c < NC; c++) s += expf(r[c] - mx);
    pos[n] = rl;
    float ce = mx + logf(s) - rl;
    if (mask[n] != 0) atomicAdd(&Ncnt[l], 1);
    __shared__ float red[256];
    red[tid] = ce;
    __syncthreads();
    for (int st = 128; st > 0; st >>= 1) {
      if (tid < st) red[tid] += red[tid + st];
      __syncthreads();
    }
    if (tid == 0) atomicAdd(ceAcc, red[0]);
  } else if (blk == 16) {                      // deterministic compaction
    __shared__ int cnt2[256];
    int base = tid * 16;
    int c = 0;
    for (int i = 0; i < 16; i++) c += (mask[base + i] != 0) ? 1 : 0;
    cnt2[tid] = c;
    __syncthreads();
    for (int s = 1; s < 256; s <<= 1) {
      int v = (tid >= s) ? cnt2[tid - s] : 0;
      __syncthreads();
      cnt2[tid] += v;
      __syncthreads();
    }
    int off = cnt2[tid] - c;
    for (int i = 0; i < 16; i++) {
      int idx = base + i;
      if (mask[idx] != 0) list[off++] = idx;
    }
    if (tid == 255) *Mcount = cnt2[255];
  } else {                                     // class aggregates
    __shared__ int eb[100], db[10];
    for (int b = tid; b < 100; b += 256) eb[b] = 0;
    if (tid < 10) db[tid] = 0;
    __syncthreads();
    int r = (blk - 17) * 256 + tid;
    int c[10];
#pragma unroll
    for (int i = 0; i < NC; i++) c[i] = cnt[i * NN + r];
    int sI[55];
    {
      int k = 0;
#pragma unroll
      for (int i = 0; i < NC; i++)
#pragma unroll
        for (int j = i; j < NC; j++) { sI[k] = c[i] * c[j]; k++; }
    }
#pragma unroll
    for (int k = 0; k < 55; k++) {
      int v = sI[k];
      for (int d = 1; d < 64; d <<= 1) v += __shfl_xor(v, d);
      sI[k] = v;
    }
    if ((tid & 63) == 0) {
      int k = 0;
      for (int i = 0; i < NC; i++)
        for (int j = i; j < NC; j++) {
          u64 v = (u64)(unsigned int)sI[k];
          if (v) {
            atomicAdd(&gSI[i * NC + j], v);
            if (i != j) atomicAdd(&gSI[j * NC + i], v);
          }
          k++;
        }
    }
    if (mask[r] != 0) {
      int lr = labels[r];
      atomicAdd(&db[lr], deg[r]);
      int selfr = (int)((bits[(size_t)r * NW + (r >> 6)] >> (r & 63)) & 1ULL);
      if (!selfr) {
#pragma unroll
        for (int i = 0; i < NC; i++)
          if (c[i]) atomicAdd(&eb[i * NC + lr], c[i]);
      }
    }
    __syncthreads();
    for (int b = tid; b < 100; b += 256) if (eb[b]) atomicAdd(&gE[b], eb[b]);
    if (tid < 10 && db[tid]) atomicAdd(&gD[tid], db[tid]);
  }
}

// ---- kernel 3: wave-autonomous 32x32 pair tiles, full load prefetch -------
// R8 structure (1 tile/wave, no barriers in loop, no per-pair atomics) with
// the serial chains removed: ALL staging loads (4 chunks, 32x dwordx4) are
// issued up front; LDS writes are b128 into a row-pair-major layout
// TBW[ypair][physrow] with physrow = r^((r>>2)&7) -> every ds_write_b128 and
// ds_read_b128 hits 8 distinct bank-quads (verified lane-by-lane).
// Epilogue scatter (adjacency words + preds) issued under the last chunk.
__global__ __launch_bounds__(256, 2) void pair_kernel(
    const u64* __restrict__ bits, const int* __restrict__ deg,
    const float* __restrict__ pos, const float* __restrict__ preds,
    const int* __restrict__ labels, const int* __restrict__ list,
    const int* __restrict__ Mcount, const int* __restrict__ Ncnt,
    const u64* __restrict__ gSI, const int* __restrict__ gE,
    const int* __restrict__ gD, float* __restrict__ gLoss) {
  __shared__ __align__(16) ulonglong2 TBW[4][8][64];   // 32 KB
  __shared__ int mNode[4][64], mLab[4][64], mDeg[4][64], mSelf[4][64];
  __shared__ float mPos[4][64];
  __shared__ float wLDS[100];
  __shared__ float wred[4];

  int tid = threadIdx.x;
  int wv = tid >> 6, lane = tid & 63;

  // class-pair weights from exact integer aggregates (gate + PER/(Ni*Nj))
  if (tid < 100) {
    int i = tid / NC, j = tid - (tid / NC) * NC;
    s64 SI = (s64)gSI[tid];
    s64 ssub = (s64)gD[i] * (s64)Ncnt[j] - SI - (s64)gE[tid];
    float w = 0.f;
    if (i != j && ssub > 0 && SI > 0) {
      float Ni = fmaxf((float)Ncnt[i], 1.f);
      float Nj = fmaxf((float)Ncnt[j], 1.f);
      w = 0.001f / (Ni * Nj);
    }
    wLDS[tid] = w;
  }
  __syncthreads();

  int M = *Mcount;
  int ntp = (M + BH - 1) / BH;
  int ntiles = (ntp * (ntp + 1)) >> 1;
  int gw = blockIdx.x * 4 + wv;
  int nw = gridDim.x * 4;

  int lp = lane >> 3, lq = lane & 7;          // 8x8 lane grid, 4x4 pairs each
  int phMy = lane ^ ((lane >> 2) & 7);        // my staging phys row
  int phP[4], phQ[4];
#pragma unroll
  for (int i = 0; i < 4; i++) {
    int r = 4 * lp + i;  phP[i] = r ^ ((r >> 2) & 7);
    int s = 32 + 4 * lq + i;  phQ[i] = s ^ ((s >> 2) & 7);
  }

  float lsum = 0.f;

  for (int t = gw; t < ntiles; t += nw) {
    int tp = 0, rem = t;
    while (rem >= ntp - tp) { rem -= ntp - tp; tp++; }
    int tq = tp + rem;
    bool diag = (tp == tq);

    // per-row metadata (lane owns row `lane`: 0-31 P band, 32-63 Q band)
    int mi = (lane < BH) ? (tp * BH + lane) : (tq * BH + (lane - BH));
    int nd = (mi < M) ? list[mi] : -1;
    int nd0 = (nd >= 0) ? nd : 0;
    mNode[wv][lane] = nd;
    mLab[wv][lane]  = (nd >= 0) ? labels[nd] : -1;
    mDeg[wv][lane]  = (nd >= 0) ? deg[nd] : 0;
    mPos[wv][lane]  = (nd >= 0) ? pos[nd] : 0.f;
    mSelf[wv][lane] = (nd >= 0) ? (int)((bits[(size_t)nd * NW + (nd >> 6)] >> (nd & 63)) & 1ULL) : 0;

    // issue ALL staging loads up front (32 x dwordx4 in flight)
    const ulonglong2* rp2 = (const ulonglong2*)(bits + (size_t)nd0 * NW);
    bool live = (nd >= 0);
    ulonglong2 pf[NCHUNK][8];
#pragma unroll
    for (int c = 0; c < NCHUNK; c++)
#pragma unroll
      for (int x = 0; x < 8; x++)
        pf[c][x] = live ? rp2[c * 8 + x] : make_ulonglong2(0ULL, 0ULL);

    asm volatile("s_waitcnt lgkmcnt(0)" ::: "memory");  // meta visible wave-wide

    int acc[4][4];
#pragma unroll
    for (int i = 0; i < 4; i++)
#pragma unroll
      for (int j = 0; j < 4; j++) acc[i][j] = 0;

    int pgR[4], qgR[4], liE[4], ljE[4];
    u64 rwpE[4][4], rwqE[4][4];
    float efE[4][4], erE[4][4];

    for (int c = 0; c < NCHUNK; c++) {
      // stage chunk c: 8 b128 writes, conflict-free phys-row layout
#pragma unroll
      for (int x = 0; x < 8; x++)
        TBW[wv][x][phMy] = pf[c][x];
      if (c == NCHUNK - 1) {
        // epilogue scatter prefetch: hidden under the last popc chunk
#pragma unroll
        for (int i = 0; i < 4; i++) { pgR[i] = mNode[wv][4 * lp + i]; liE[i] = mLab[wv][4 * lp + i]; }
#pragma unroll
        for (int j = 0; j < 4; j++) { qgR[j] = mNode[wv][32 + 4 * lq + j]; ljE[j] = mLab[wv][32 + 4 * lq + j]; }
#pragma unroll
        for (int i = 0; i < 4; i++) {
          int pg = (pgR[i] >= 0) ? pgR[i] : 0;
          int lic = (liE[i] >= 0) ? liE[i] : 0;
#pragma unroll
          for (int j = 0; j < 4; j++) {
            int qg = (qgR[j] >= 0) ? qgR[j] : 0;
            int ljc = (ljE[j] >= 0) ? ljE[j] : 0;
            rwpE[i][j] = bits[(size_t)pg * NW + (qg >> 6)];
            rwqE[i][j] = bits[(size_t)qg * NW + (pg >> 6)];
            efE[i][j] = preds[qg * NC + lic];
            erE[i][j] = preds[pg * NC + ljc];
          }
        }
      }
      // wave-synchronous: drain DS writes before reads (no block barrier)
      asm volatile("s_waitcnt lgkmcnt(0)" ::: "memory");
      __builtin_amdgcn_sched_barrier(0);

#pragma unroll
      for (int y = 0; y < 8; y++) {           // 8 row-pair words per chunk
        ulonglong2 P[4], Q[4];
#pragma unroll
        for (int i = 0; i < 4; i++) P[i] = TBW[wv][y][phP[i]];
#pragma unroll
        for (int j = 0; j < 4; j++) Q[j] = TBW[wv][y][phQ[j]];
#pragma unroll
        for (int i = 0; i < 4; i++)
#pragma unroll
          for (int j = 0; j < 4; j++)
            acc[i][j] += (int)__popcll(P[i].x & Q[j].x)
                       + (int)__popcll(P[i].y & Q[j].y);
      }
    }

    // epilogue: registers + per-wave meta LDS only
#pragma unroll
    for (int i = 0; i < 4; i++) {
      if (pgR[i] < 0) continue;
      int pl = 4 * lp + i;
      int li = liE[i];
      int dgp = mDeg[wv][pl];
      int sp  = mSelf[wv][pl];
      float pp = mPos[wv][pl];
#pragma unroll
      for (int j = 0; j < 4; j++) {
        if (qgR[j] < 0) continue;
        int lj = ljE[j];
        if (li == lj) continue;               // off-diag class bins only
        int qr = 4 * lq + j;
        if (diag && pl >= qr) continue;       // unordered once on diag tiles
        int inter = acc[i][j];
        int apq = (int)((rwpE[i][j] >> (qgR[j] & 63)) & 1ULL);
        int aqp = (int)((rwqE[i][j] >> (pgR[i] & 63)) & 1ULL);
        int sq  = mSelf[wv][32 + qr];
        int sub_f = dgp - inter - (apq & (sq ^ 1));
        int sub_r = mDeg[wv][32 + qr] - inter - (aqp & (sp ^ 1));
        float rden = 1.f / (1.f + S1F * (float)inter);
        float xf = (1.f + S1F * (float)sub_f) * rden;
        float xr = (1.f + S1F * (float)sub_r) * rden;
        float Ef = __expf(efE[i][j] - pp);
        float Er = __expf(erE[i][j] - mPos[wv][32 + qr]);
        float vf = 1.f / (1.f + __expf(xf));  // 1 - sigmoid(x)
        float vr = 1.f / (1.f + __expf(xr));
        lsum += Ef * vf * wLDS[li * NC + lj] + Er * vr * wLDS[lj * NC + li];
      }
    }
    // next tile: wave-order DS makes LDS rewrite safe without barriers
  }

  // block reduce: wave shuffle -> 4 partials -> one atomic
  for (int d = 1; d < 64; d <<= 1) lsum += __shfl_xor(lsum, d);
  if (lane == 0) wred[wv] = lsum;
  __syncthreads();
  if (tid == 0) atomicAdd(gLoss, wred[0] + wred[1] + wred[2] + wred[3]);
}

// ---- kernel 4: final assembly ---------------------------------------------
__global__ void fin_kernel(const float* __restrict__ ceAcc,
                           const float* __restrict__ gLoss,
                           float* __restrict__ out) {
  out[0] = ceAcc[0] / (float)NN + gLoss[0];
}

// ---- launch ---------------------------------------------------------------
extern "C" void kernel_launch(void* const* d_in, const int* in_sizes, int n_in,
                              void* d_out, int out_size, void* d_ws, size_t ws_size,
                              hipStream_t stream) {
  const float* preds  = (const float*)d_in[0];
  const int*   labels = (const int*)d_in[1];
  const int*   mask   = (const int*)d_in[2];
  const int*   adj    = (const int*)d_in[3];

  char* ws = (char*)d_ws;
  u64*   bits  = (u64*)(ws + OFF_BITS);
  int*   deg   = (int*)(ws + OFF_DEG);
  float* pos   = (float*)(ws + OFF_POS);
  int*   list  = (int*)(ws + OFF_LIST);
  char*  accb  = ws + OFF_ACC;
  float* ceAcc = (float*)(accb + A_CE);
  float* gLoss = (float*)(accb + A_LOSS);
  int*   Mcnt  = (int*)(accb + A_MCNT);
  int*   Ncnt  = (int*)(accb + A_NCNT);
  int*   gD    = (int*)(accb + A_GD);
  int*   gE    = (int*)(accb + A_GE);
  u64*   gSI   = (u64*)(accb + A_GSI);
  int*   cnt   = (int*)(ws + OFF_CNT);

  hipMemsetAsync(ws + OFF_ACC, 0, 1536 + 163840, stream);

  hipLaunchKernelGGL(pack_bits_kernel, dim3(NN), dim3(256), 0, stream,
                     adj, bits, deg, cnt, labels, mask);
  hipLaunchKernelGGL(mid_kernel, dim3(33), dim3(256), 0, stream,
                     preds, labels, mask, bits, deg, cnt,
                     pos, Ncnt, ceAcc, list, Mcnt, gSI, gE, gD);
  // M=2048 -> 2080 tiles; 520 blocks x 4 waves = 2080 (1 tile/wave);
  // wave-stride covers larger M.
  hipLaunchKernelGGL(pair_kernel, dim3(520), dim3(256), 0, stream,
                     bits, deg, pos, preds, labels, list, Mcnt, Ncnt,
                     gSI, gE, gD, gLoss);
  hipLaunchKernelGGL(fin_kernel, dim3(1), dim3(1), 0, stream,
                     ceAcc, gLoss, (float*)d_out);
}